// Round 1
// baseline (364.797 us; speedup 1.0000x reference)
//
#include <hip/hip_runtime.h>
#include <math.h>

// Problem constants (fixed by setup_inputs)
#define NENT 50000
#define DD   32      // d_e = d_r = RANK = 32
#define BSZ  64
#define NI   1024
#define NROWS 65536  // 2 * 32 * 1024 row-sums
#define EPS  1e-5f

// workspace layout (float offsets)
#define WS_U12S 0        // 32768: u12[r,i] = sum_c U12[r,i,c]
#define WS_U3S  32768    // 32768: u3[r,j]  = sum_c U3R[r,j,c]
#define WS_P    65536    // 32
#define WS_A    65568    // 2048: a[b,r]
#define WS_RE   67616    // 2048: r_emb (BN'd)
#define WS_E2   69664    // 2048
#define WS_E3   71712    // 2048
#define WS_VEC  73760    // 2048: atomic-accumulated vec[b,k]
#define WS_SUM  75808    // 64: 1/denominator per row (written by k3b)
#define WS_VECN 75872    // 2048: BN'd vec (written by k3b)
#define WS_PART 77920    // 196*64 = 12544: per-(nchunk,b) partial sums
#define NCHUNK  196      // 196*256 = 50176 >= 50000 n-columns

// ---- BN over batch dim (B=64) for a gathered (B,32) matrix, two-pass ----
__device__ void bn_block(const float* __restrict__ src, const int* __restrict__ idx,
                         const float* __restrict__ g, const float* __restrict__ bb,
                         float* __restrict__ dst, float* xs, float* st) {
    for (int i = threadIdx.x; i < BSZ * DD; i += 256) {
        int b = i >> 5, d = i & 31;
        xs[i] = src[(size_t)idx[b] * DD + d];
    }
    __syncthreads();
    if (threadIdx.x < DD) {
        int d = threadIdx.x;
        float m = 0.f;
        for (int b = 0; b < BSZ; ++b) m += xs[b * 32 + d];
        m *= (1.f / 64.f);
        float v = 0.f;
        for (int b = 0; b < BSZ; ++b) { float t = xs[b * 32 + d] - m; v += t * t; }
        v *= (1.f / 64.f);
        st[d]      = m;
        st[32 + d] = g[d] / sqrtf(v + EPS);
    }
    __syncthreads();
    for (int i = threadIdx.x; i < BSZ * DD; i += 256) {
        int d = i & 31;
        dst[i] = (xs[i] - st[d]) * st[32 + d] + bb[d];
    }
    __syncthreads();
}

// ---- K1: persistent streaming row-sums (268 MB, the roofline) + fused prep ----
__global__ __launch_bounds__(256) void k1_rowsums(
    const float* __restrict__ U12, const float* __restrict__ U3R,
    const float* __restrict__ R, const float* __restrict__ E,
    const float* __restrict__ U_root, const float* __restrict__ P,
    const float* __restrict__ g_r, const float* __restrict__ b_r,
    const float* __restrict__ g_e, const float* __restrict__ b_e,
    const int* __restrict__ r_idx, const int* __restrict__ e2_idx,
    const int* __restrict__ e3_idx, float* __restrict__ ws) {
    __shared__ float xs[BSZ * DD];
    __shared__ float st[64];
    int blk = blockIdx.x;
    if (blk < 2048) {
        int w = blk * 4 + (threadIdx.x >> 6);   // wave id, 0..8191
        int lane = threadIdx.x & 63;
        const float* base = (w < 4096) ? U12 : U3R;
        size_t lrow0 = (w < 4096) ? (size_t)w * 8 : ((size_t)w * 8 - 32768);
        int grow0 = w * 8;                      // global ws row index
        const float4* src = (const float4*)base + lrow0 * 256 + lane;
#pragma unroll 2
        for (int p = 0; p < 4; ++p) {
            const float4* pa = src + (size_t)(2 * p) * 256;
            float4 a0 = pa[0],   a1 = pa[64],  a2 = pa[128], a3 = pa[192];
            float4 c0 = pa[256], c1 = pa[320], c2 = pa[384], c3 = pa[448];
            float sa = ((a0.x + a0.y) + (a0.z + a0.w)) + ((a1.x + a1.y) + (a1.z + a1.w))
                     + ((a2.x + a2.y) + (a2.z + a2.w)) + ((a3.x + a3.y) + (a3.z + a3.w));
            float sb = ((c0.x + c0.y) + (c0.z + c0.w)) + ((c1.x + c1.y) + (c1.z + c1.w))
                     + ((c2.x + c2.y) + (c2.z + c2.w)) + ((c3.x + c3.y) + (c3.z + c3.w));
            // pair-merged butterfly: 6 hops reduce BOTH rows
            float mine  = (lane < 32) ? sa : sb;
            float other = __shfl_xor((lane < 32) ? sb : sa, 32, 64);
            float comb = mine + other;
#pragma unroll
            for (int o = 16; o; o >>= 1) comb += __shfl_xor(comb, o, 64);
            if (lane == 0)  ws[grow0 + 2 * p]     = comb;
            if (lane == 32) ws[grow0 + 2 * p + 1] = comb;
        }
        return;
    }
    // ---- fused prep block (runs concurrently with streaming blocks) ----
    int tid = threadIdx.x;
    float* wp   = ws + WS_P;
    float* wa   = ws + WS_A;
    float* wvec = ws + WS_VEC;
    if (tid < 32) {                       // p[r] = sum_c P[r,c]
        float s = 0.f;
#pragma unroll
        for (int c = 0; c < 32; ++c) s += P[tid * 32 + c];
        wp[tid] = s;
    }
    for (int i = tid; i < BSZ * DD; i += 256) {   // a[b,r] = sum_c U_root[r_idx[b],r,c]
        int b = i >> 5, r = i & 31;
        const float* u = U_root + (size_t)r_idx[b] * (DD * DD) + r * 32;
        float s = 0.f;
#pragma unroll
        for (int c = 0; c < 32; ++c) s += u[c];
        wa[i]   = s;
        wvec[i] = 0.f;                    // zero the atomic accumulator for k2b
    }
    bn_block(R, r_idx,  g_r, b_r, ws + WS_RE, xs, st);
    bn_block(E, e2_idx, g_e, b_e, ws + WS_E2, xs, st);
    bn_block(E, e3_idx, g_e, b_e, ws + WS_E3, xs, st);
}

// ---- K2b: alpha[b,r], beta[b,r,k], accumulate a*p*alpha*beta into vec[b,k] ----
__global__ __launch_bounds__(256) void k2b_core(float* __restrict__ ws) {
    const float* u12s = ws + WS_U12S;
    const float* u3s  = ws + WS_U3S;
    const float* wp   = ws + WS_P;
    const float* wa   = ws + WS_A;
    const float* wre  = ws + WS_RE;
    const float* we2  = ws + WS_E2;
    const float* we3  = ws + WS_E3;
    float* wvec = ws + WS_VEC;
    int lane = threadIdx.x & 63;
    int pair = blockIdx.x * 4 + (threadIdx.x >> 6);   // 2048 (b,r) pairs
    int b = pair >> 5, r = pair & 31;
    float e2v = we2[b * 32 + (lane & 31)];
    const float* u12r = u12s + r * NI;
    float acc = 0.f;
#pragma unroll
    for (int t = 0; t < 16; ++t) {
        int di = t * 64 + lane;
        acc += u12r[di] * wre[b * 32 + (di >> 5)] * e2v;
    }
#pragma unroll
    for (int o = 32; o; o >>= 1) acc += __shfl_xor(acc, o, 64);   // all lanes hold alpha
    int k = lane & 31, j0 = (lane >> 5) * 16;
    const float* u3r = u3s + r * NI;
    float bacc = 0.f;
#pragma unroll
    for (int jj = 0; jj < 16; ++jj) {
        int j = j0 + jj;
        bacc += we3[b * 32 + j] * u3r[j * 32 + k];
    }
    bacc += __shfl_down(bacc, 32, 64);
    if (lane < 32) {
        float coef = wa[b * 32 + r] * wp[r] * acc;
        atomicAdd(&wvec[b * 32 + k], coef * bacc);   // 2048 distinct addrs, no contention
    }
}

// ---- K3a: logits + exp, SUMS ONLY (no store). Per-block BN of vec.        ----
// grid 392: q>>1 = n-chunk (256 cols), q&1 = b-half (32 b's). No atomics:
// butterfly leaves wave-sum in all lanes; lane (b-b0) keeps it in 1 VGPR.
__global__ __launch_bounds__(256) void k3a_sums(const float* __restrict__ E,
                                                const float* __restrict__ g_w,
                                                const float* __restrict__ b_w,
                                                float* __restrict__ ws) {
    __shared__ float vs[BSZ * DD];
    __shared__ float st[64];
    __shared__ float part[4][32];
    const float* wvec = ws + WS_VEC;
    int t = threadIdx.x;
    for (int i = t; i < BSZ * DD; i += 256) vs[i] = wvec[i];
    __syncthreads();
    if (t < DD) {                 // redundant per-block BN (trivial cost)
        float m = 0.f;
        for (int b = 0; b < BSZ; ++b) m += vs[b * 32 + t];
        m *= (1.f / 64.f);
        float v = 0.f;
        for (int b = 0; b < BSZ; ++b) { float d = vs[b * 32 + t] - m; v += d * d; }
        v *= (1.f / 64.f);
        st[t]      = m;
        st[32 + t] = g_w[t] / sqrtf(v + EPS);
    }
    __syncthreads();
    for (int i = t; i < BSZ * DD; i += 256) {
        int d = i & 31;
        vs[i] = (vs[i] - st[d]) * st[32 + d] + b_w[d];
    }
    __syncthreads();
    int q = blockIdx.x;
    int nchunk = q >> 1, b0 = (q & 1) * 32;
    int n = nchunk * 256 + t;
    int lane = t & 63, w = t >> 6;
    bool valid = n < NENT;
    int nc = valid ? n : (NENT - 1);
    float4 er[8];
    const float4* ep = (const float4*)(E + (size_t)nc * DD);
#pragma unroll
    for (int qq = 0; qq < 8; ++qq) er[qq] = ep[qq];
    float pacc = 0.f;
#pragma unroll 4
    for (int j = 0; j < 32; ++j) {
        int b = b0 + j;
        const float4* vp = (const float4*)(vs + b * 32);
        float acc = 0.f;
#pragma unroll
        for (int qq = 0; qq < 8; ++qq) {
            float4 vv = vp[qq];
            acc += er[qq].x * vv.x + er[qq].y * vv.y + er[qq].z * vv.z + er[qq].w * vv.w;
        }
        float e = valid ? __expf(acc) : 0.f;
#pragma unroll
        for (int o = 32; o; o >>= 1) e += __shfl_xor(e, o, 64);  // full wave sum, all lanes
        pacc = (lane == j) ? e : pacc;   // lane j archives b0+j's wave-sum
    }
    if (lane < 32) part[w][lane] = pacc;
    __syncthreads();
    if (t < 32) {
        float s = part[0][t] + part[1][t] + part[2][t] + part[3][t];
        ws[WS_PART + nchunk * 64 + b0 + t] = s;   // distinct addr per (nchunk,b)
    }
}

// ---- K3b: 1 block. (a) reduce partials -> inv[b]; (b) BN(vec) -> vecn ----
__global__ __launch_bounds__(256) void k3b_finish(const float* __restrict__ g_w,
                                                  const float* __restrict__ b_w,
                                                  float* __restrict__ ws) {
    __shared__ float red[4][64];
    __shared__ float xs[BSZ * DD];
    __shared__ float st[64];
    int t = threadIdx.x;
    int b = t & 63, chunk = t >> 6;                  // 4 chunks x 49 = 196
    const float* pp = ws + WS_PART;
    float s = 0.f;
    for (int p = chunk * 49; p < chunk * 49 + 49; ++p) s += pp[p * 64 + b];
    red[chunk][b] = s;
    // BN of vec while partial-reduce settles
    const float* wvec = ws + WS_VEC;
    for (int i = t; i < BSZ * DD; i += 256) xs[i] = wvec[i];
    __syncthreads();
    if (t < 64) {
        float tot = red[0][t] + red[1][t] + red[2][t] + red[3][t];
        ws[WS_SUM + t] = 1.0f / tot;
    }
    if (t < DD) {
        float m = 0.f;
        for (int bb = 0; bb < BSZ; ++bb) m += xs[bb * 32 + t];
        m *= (1.f / 64.f);
        float v = 0.f;
        for (int bb = 0; bb < BSZ; ++bb) { float d = xs[bb * 32 + t] - m; v += d * d; }
        v *= (1.f / 64.f);
        st[t]      = m;
        st[32 + t] = g_w[t] / sqrtf(v + EPS);
    }
    __syncthreads();
    for (int i = t; i < BSZ * DD; i += 256) {
        int d = i & 31;
        ws[WS_VECN + i] = (xs[i] - st[d]) * st[32 + d] + b_w[d];
    }
}

// ---- K3c: recompute logits, write exp(logit)*inv once (single output pass) ----
__global__ __launch_bounds__(256) void k3c_write(const float* __restrict__ E,
                                                 const float* __restrict__ ws,
                                                 float* __restrict__ out) {
    __shared__ float vs[BSZ * DD];
    __shared__ float iv[64];
    int t = threadIdx.x;
    for (int i = t; i < BSZ * DD; i += 256) vs[i] = ws[WS_VECN + i];
    if (t < 64) iv[t] = ws[WS_SUM + t];
    __syncthreads();
    int q = blockIdx.x;
    int nchunk = q >> 1, b0 = (q & 1) * 32;
    int n = nchunk * 256 + t;
    if (n >= NENT) return;
    float4 er[8];
    const float4* ep = (const float4*)(E + (size_t)n * DD);
#pragma unroll
    for (int qq = 0; qq < 8; ++qq) er[qq] = ep[qq];
#pragma unroll 4
    for (int j = 0; j < 32; ++j) {
        int b = b0 + j;
        const float4* vp = (const float4*)(vs + b * 32);
        float acc = 0.f;
#pragma unroll
        for (int qq = 0; qq < 8; ++qq) {
            float4 vv = vp[qq];
            acc += er[qq].x * vv.x + er[qq].y * vv.y + er[qq].z * vv.z + er[qq].w * vv.w;
        }
        out[(size_t)b * NENT + n] = __expf(acc) * iv[b];
    }
}

extern "C" void kernel_launch(void* const* d_in, const int* in_sizes, int n_in,
                              void* d_out, int out_size, void* d_ws, size_t ws_size,
                              hipStream_t stream) {
    (void)in_sizes; (void)n_in; (void)out_size; (void)ws_size;
    const float* E      = (const float*)d_in[0];
    const float* R      = (const float*)d_in[1];
    const float* U_root = (const float*)d_in[2];
    const float* U12    = (const float*)d_in[3];
    const float* U3R    = (const float*)d_in[4];
    const float* P      = (const float*)d_in[5];
    const float* g_r    = (const float*)d_in[6];
    const float* b_r    = (const float*)d_in[7];
    const float* g_e    = (const float*)d_in[8];
    const float* b_e    = (const float*)d_in[9];
    const float* g_w    = (const float*)d_in[10];
    const float* b_w    = (const float*)d_in[11];
    const int* r_idx    = (const int*)d_in[12];
    const int* e2_idx   = (const int*)d_in[13];
    const int* e3_idx   = (const int*)d_in[14];
    float* ws  = (float*)d_ws;
    float* out = (float*)d_out;

    k1_rowsums<<<dim3(2049), dim3(256), 0, stream>>>(
        U12, U3R, R, E, U_root, P, g_r, b_r, g_e, b_e, r_idx, e2_idx, e3_idx, ws);
    k2b_core<<<dim3(512), dim3(256), 0, stream>>>(ws);
    k3a_sums<<<dim3(2 * NCHUNK), dim3(256), 0, stream>>>(E, g_w, b_w, ws);
    k3b_finish<<<dim3(1), dim3(256), 0, stream>>>(g_w, b_w, ws);
    k3c_write<<<dim3(2 * NCHUNK), dim3(256), 0, stream>>>(E, ws, out);
}

// Round 2
// 362.745 us; speedup vs baseline: 1.0057x; 1.0057x over previous
//
#include <hip/hip_runtime.h>
#include <math.h>

// Problem constants (fixed by setup_inputs)
#define NENT 50000
#define DD   32      // d_e = d_r = RANK = 32
#define BSZ  64
#define NI   1024
#define NROWS 65536  // 2 * 32 * 1024 row-sums
#define EPS  1e-5f

// workspace layout (float offsets)
#define WS_U12S 0        // 32768: u12[r,i] = sum_c U12[r,i,c]
#define WS_U3S  32768    // 32768: u3[r,j]  = sum_c U3R[r,j,c]
#define WS_P    65536    // 32
#define WS_A    65568    // 2048: a[b,r]
#define WS_RE   67616    // 2048: r_emb (BN'd)
#define WS_E2   69664    // 2048
#define WS_E3   71712    // 2048
#define WS_VEC  73760    // 2048: atomic-accumulated vec[b,k]
#define WS_SUM  75808    // 64: 1/denominator per row (written by k3b)
#define WS_VECN 75872    // 2048: BN'd vec (written by k3b)
#define WS_PART 77920    // 196*64 = 12544: per-(nchunk,b) partial sums
#define NCHUNK  196      // 196*256 = 50176 >= 50000 n-columns

// ---- BN over batch dim (B=64) for a gathered (B,32) matrix, two-pass ----
__device__ void bn_block(const float* __restrict__ src, const int* __restrict__ idx,
                         const float* __restrict__ g, const float* __restrict__ bb,
                         float* __restrict__ dst, float* xs, float* st) {
    for (int i = threadIdx.x; i < BSZ * DD; i += 256) {
        int b = i >> 5, d = i & 31;
        xs[i] = src[(size_t)idx[b] * DD + d];
    }
    __syncthreads();
    if (threadIdx.x < DD) {
        int d = threadIdx.x;
        float m = 0.f;
        for (int b = 0; b < BSZ; ++b) m += xs[b * 32 + d];
        m *= (1.f / 64.f);
        float v = 0.f;
        for (int b = 0; b < BSZ; ++b) { float t = xs[b * 32 + d] - m; v += t * t; }
        v *= (1.f / 64.f);
        st[d]      = m;
        st[32 + d] = g[d] / sqrtf(v + EPS);
    }
    __syncthreads();
    for (int i = threadIdx.x; i < BSZ * DD; i += 256) {
        int d = i & 31;
        dst[i] = (xs[i] - st[d]) * st[32 + d] + bb[d];
    }
    __syncthreads();
}

// ---- K1: streaming row-sums as a COMPACT SWEEPING FRONT + fused prep ----
// 1024 streaming blocks x 4 waves; each wave does 8 rounds of one ROW PAIR
// (8 KB). Round p: all 4096 waves read the contiguous 32 MB window
// rows [p*8192, (p+1)*8192) -> DRAM-friendly sweep. Double-buffered register
// pipeline: round p+1's 8 loads are in flight while round p reduces.
#define HADD4(v) (((v).x + (v).y) + ((v).z + (v).w))

#define LOADP(p, buf) do {                                                      \
    const float4* _s = (((p) < 4)                                               \
        ? (u12v + (((size_t)(p) * 4096 + (size_t)w) * 512))                     \
        : (u3v  + (((size_t)((p) - 4) * 4096 + (size_t)w) * 512))) + lane;      \
    _Pragma("unroll")                                                           \
    for (int _i = 0; _i < 8; ++_i) (buf)[_i] = _s[(size_t)_i * 64];             \
} while (0)

#define REDSTORE(p, buf) do {                                                   \
    float _sa = HADD4((buf)[0]) + HADD4((buf)[1]) + HADD4((buf)[2]) + HADD4((buf)[3]); \
    float _sb = HADD4((buf)[4]) + HADD4((buf)[5]) + HADD4((buf)[6]) + HADD4((buf)[7]); \
    float _mine  = (lane < 32) ? _sa : _sb;                                     \
    float _other = __shfl_xor((lane < 32) ? _sb : _sa, 32, 64);                 \
    float _comb = _mine + _other;                                               \
    _Pragma("unroll")                                                           \
    for (int _o = 16; _o; _o >>= 1) _comb += __shfl_xor(_comb, _o, 64);         \
    int _grow = ((p) * 4096 + w) * 2;                                           \
    if (lane == 0)  ws[_grow]     = _comb;                                      \
    if (lane == 32) ws[_grow + 1] = _comb;                                      \
} while (0)

__global__ __launch_bounds__(256, 4) void k1_rowsums(
    const float* __restrict__ U12, const float* __restrict__ U3R,
    const float* __restrict__ R, const float* __restrict__ E,
    const float* __restrict__ U_root, const float* __restrict__ P,
    const float* __restrict__ g_r, const float* __restrict__ b_r,
    const float* __restrict__ g_e, const float* __restrict__ b_e,
    const int* __restrict__ r_idx, const int* __restrict__ e2_idx,
    const int* __restrict__ e3_idx, float* __restrict__ ws) {
    __shared__ float xs[BSZ * DD];
    __shared__ float st[64];
    int blk = blockIdx.x;
    if (blk < 1024) {
        int w = blk * 4 + (threadIdx.x >> 6);   // wave id, 0..4095
        int lane = threadIdx.x & 63;
        const float4* u12v = (const float4*)U12;
        const float4* u3v  = (const float4*)U3R;
        float4 A[8], Bv[8];
        LOADP(0, A);
        LOADP(1, Bv);
#pragma unroll
        for (int p = 0; p < 8; p += 2) {
            // reduce A (round p); loads for p+1 already in flight in Bv
            if (p + 2 < 8) { REDSTORE(p, A); LOADP(p + 2, A); }
            else            REDSTORE(p, A);
            if (p + 3 < 8) { REDSTORE(p + 1, Bv); LOADP(p + 3, Bv); }
            else            REDSTORE(p + 1, Bv);
        }
        return;
    }
    // ---- fused prep block (runs concurrently with streaming blocks) ----
    int tid = threadIdx.x;
    float* wp   = ws + WS_P;
    float* wa   = ws + WS_A;
    float* wvec = ws + WS_VEC;
    if (tid < 32) {                       // p[r] = sum_c P[r,c]
        float s = 0.f;
#pragma unroll
        for (int c = 0; c < 32; ++c) s += P[tid * 32 + c];
        wp[tid] = s;
    }
    for (int i = tid; i < BSZ * DD; i += 256) {   // a[b,r] = sum_c U_root[r_idx[b],r,c]
        int b = i >> 5, r = i & 31;
        const float* u = U_root + (size_t)r_idx[b] * (DD * DD) + r * 32;
        float s = 0.f;
#pragma unroll
        for (int c = 0; c < 32; ++c) s += u[c];
        wa[i]   = s;
        wvec[i] = 0.f;                    // zero the atomic accumulator for k2b
    }
    bn_block(R, r_idx,  g_r, b_r, ws + WS_RE, xs, st);
    bn_block(E, e2_idx, g_e, b_e, ws + WS_E2, xs, st);
    bn_block(E, e3_idx, g_e, b_e, ws + WS_E3, xs, st);
}

// ---- K2b: alpha[b,r], beta[b,r,k], accumulate a*p*alpha*beta into vec[b,k] ----
__global__ __launch_bounds__(256) void k2b_core(float* __restrict__ ws) {
    const float* u12s = ws + WS_U12S;
    const float* u3s  = ws + WS_U3S;
    const float* wp   = ws + WS_P;
    const float* wa   = ws + WS_A;
    const float* wre  = ws + WS_RE;
    const float* we2  = ws + WS_E2;
    const float* we3  = ws + WS_E3;
    float* wvec = ws + WS_VEC;
    int lane = threadIdx.x & 63;
    int pair = blockIdx.x * 4 + (threadIdx.x >> 6);   // 2048 (b,r) pairs
    int b = pair >> 5, r = pair & 31;
    float e2v = we2[b * 32 + (lane & 31)];
    const float* u12r = u12s + r * NI;
    float acc = 0.f;
#pragma unroll
    for (int t = 0; t < 16; ++t) {
        int di = t * 64 + lane;
        acc += u12r[di] * wre[b * 32 + (di >> 5)] * e2v;
    }
#pragma unroll
    for (int o = 32; o; o >>= 1) acc += __shfl_xor(acc, o, 64);   // all lanes hold alpha
    int k = lane & 31, j0 = (lane >> 5) * 16;
    const float* u3r = u3s + r * NI;
    float bacc = 0.f;
#pragma unroll
    for (int jj = 0; jj < 16; ++jj) {
        int j = j0 + jj;
        bacc += we3[b * 32 + j] * u3r[j * 32 + k];
    }
    bacc += __shfl_down(bacc, 32, 64);
    if (lane < 32) {
        float coef = wa[b * 32 + r] * wp[r] * acc;
        atomicAdd(&wvec[b * 32 + k], coef * bacc);   // 2048 distinct addrs, no contention
    }
}

// ---- K3a: logits + exp, SUMS ONLY (no store). Per-block BN of vec.        ----
__global__ __launch_bounds__(256) void k3a_sums(const float* __restrict__ E,
                                                const float* __restrict__ g_w,
                                                const float* __restrict__ b_w,
                                                float* __restrict__ ws) {
    __shared__ float vs[BSZ * DD];
    __shared__ float st[64];
    __shared__ float part[4][32];
    const float* wvec = ws + WS_VEC;
    int t = threadIdx.x;
    for (int i = t; i < BSZ * DD; i += 256) vs[i] = wvec[i];
    __syncthreads();
    if (t < DD) {                 // redundant per-block BN (trivial cost)
        float m = 0.f;
        for (int b = 0; b < BSZ; ++b) m += vs[b * 32 + t];
        m *= (1.f / 64.f);
        float v = 0.f;
        for (int b = 0; b < BSZ; ++b) { float d = vs[b * 32 + t] - m; v += d * d; }
        v *= (1.f / 64.f);
        st[t]      = m;
        st[32 + t] = g_w[t] / sqrtf(v + EPS);
    }
    __syncthreads();
    for (int i = t; i < BSZ * DD; i += 256) {
        int d = i & 31;
        vs[i] = (vs[i] - st[d]) * st[32 + d] + b_w[d];
    }
    __syncthreads();
    int q = blockIdx.x;
    int nchunk = q >> 1, b0 = (q & 1) * 32;
    int n = nchunk * 256 + t;
    int lane = t & 63, w = t >> 6;
    bool valid = n < NENT;
    int nc = valid ? n : (NENT - 1);
    float4 er[8];
    const float4* ep = (const float4*)(E + (size_t)nc * DD);
#pragma unroll
    for (int qq = 0; qq < 8; ++qq) er[qq] = ep[qq];
    float pacc = 0.f;
#pragma unroll 4
    for (int j = 0; j < 32; ++j) {
        int b = b0 + j;
        const float4* vp = (const float4*)(vs + b * 32);
        float acc = 0.f;
#pragma unroll
        for (int qq = 0; qq < 8; ++qq) {
            float4 vv = vp[qq];
            acc += er[qq].x * vv.x + er[qq].y * vv.y + er[qq].z * vv.z + er[qq].w * vv.w;
        }
        float e = valid ? __expf(acc) : 0.f;
#pragma unroll
        for (int o = 32; o; o >>= 1) e += __shfl_xor(e, o, 64);  // full wave sum, all lanes
        pacc = (lane == j) ? e : pacc;   // lane j archives b0+j's wave-sum
    }
    if (lane < 32) part[w][lane] = pacc;
    __syncthreads();
    if (t < 32) {
        float s = part[0][t] + part[1][t] + part[2][t] + part[3][t];
        ws[WS_PART + nchunk * 64 + b0 + t] = s;   // distinct addr per (nchunk,b)
    }
}

// ---- K3b: 1 block. (a) reduce partials -> inv[b]; (b) BN(vec) -> vecn ----
__global__ __launch_bounds__(256) void k3b_finish(const float* __restrict__ g_w,
                                                  const float* __restrict__ b_w,
                                                  float* __restrict__ ws) {
    __shared__ float red[4][64];
    __shared__ float xs[BSZ * DD];
    __shared__ float st[64];
    int t = threadIdx.x;
    int b = t & 63, chunk = t >> 6;                  // 4 chunks x 49 = 196
    const float* pp = ws + WS_PART;
    float s = 0.f;
    for (int p = chunk * 49; p < chunk * 49 + 49; ++p) s += pp[p * 64 + b];
    red[chunk][b] = s;
    // BN of vec while partial-reduce settles
    const float* wvec = ws + WS_VEC;
    for (int i = t; i < BSZ * DD; i += 256) xs[i] = wvec[i];
    __syncthreads();
    if (t < 64) {
        float tot = red[0][t] + red[1][t] + red[2][t] + red[3][t];
        ws[WS_SUM + t] = 1.0f / tot;
    }
    if (t < DD) {
        float m = 0.f;
        for (int bb = 0; bb < BSZ; ++bb) m += xs[bb * 32 + t];
        m *= (1.f / 64.f);
        float v = 0.f;
        for (int bb = 0; bb < BSZ; ++bb) { float d = xs[bb * 32 + t] - m; v += d * d; }
        v *= (1.f / 64.f);
        st[t]      = m;
        st[32 + t] = g_w[t] / sqrtf(v + EPS);
    }
    __syncthreads();
    for (int i = t; i < BSZ * DD; i += 256) {
        int d = i & 31;
        ws[WS_VECN + i] = (xs[i] - st[d]) * st[32 + d] + b_w[d];
    }
}

// ---- K3c: recompute logits, write exp(logit)*inv once (single output pass) ----
__global__ __launch_bounds__(256) void k3c_write(const float* __restrict__ E,
                                                 const float* __restrict__ ws,
                                                 float* __restrict__ out) {
    __shared__ float vs[BSZ * DD];
    __shared__ float iv[64];
    int t = threadIdx.x;
    for (int i = t; i < BSZ * DD; i += 256) vs[i] = ws[WS_VECN + i];
    if (t < 64) iv[t] = ws[WS_SUM + t];
    __syncthreads();
    int q = blockIdx.x;
    int nchunk = q >> 1, b0 = (q & 1) * 32;
    int n = nchunk * 256 + t;
    if (n >= NENT) return;
    float4 er[8];
    const float4* ep = (const float4*)(E + (size_t)n * DD);
#pragma unroll
    for (int qq = 0; qq < 8; ++qq) er[qq] = ep[qq];
#pragma unroll 4
    for (int j = 0; j < 32; ++j) {
        int b = b0 + j;
        const float4* vp = (const float4*)(vs + b * 32);
        float acc = 0.f;
#pragma unroll
        for (int qq = 0; qq < 8; ++qq) {
            float4 vv = vp[qq];
            acc += er[qq].x * vv.x + er[qq].y * vv.y + er[qq].z * vv.z + er[qq].w * vv.w;
        }
        out[(size_t)b * NENT + n] = __expf(acc) * iv[b];
    }
}

extern "C" void kernel_launch(void* const* d_in, const int* in_sizes, int n_in,
                              void* d_out, int out_size, void* d_ws, size_t ws_size,
                              hipStream_t stream) {
    (void)in_sizes; (void)n_in; (void)out_size; (void)ws_size;
    const float* E      = (const float*)d_in[0];
    const float* R      = (const float*)d_in[1];
    const float* U_root = (const float*)d_in[2];
    const float* U12    = (const float*)d_in[3];
    const float* U3R    = (const float*)d_in[4];
    const float* P      = (const float*)d_in[5];
    const float* g_r    = (const float*)d_in[6];
    const float* b_r    = (const float*)d_in[7];
    const float* g_e    = (const float*)d_in[8];
    const float* b_e    = (const float*)d_in[9];
    const float* g_w    = (const float*)d_in[10];
    const float* b_w    = (const float*)d_in[11];
    const int* r_idx    = (const int*)d_in[12];
    const int* e2_idx   = (const int*)d_in[13];
    const int* e3_idx   = (const int*)d_in[14];
    float* ws  = (float*)d_ws;
    float* out = (float*)d_out;

    k1_rowsums<<<dim3(1025), dim3(256), 0, stream>>>(
        U12, U3R, R, E, U_root, P, g_r, b_r, g_e, b_e, r_idx, e2_idx, e3_idx, ws);
    k2b_core<<<dim3(512), dim3(256), 0, stream>>>(ws);
    k3a_sums<<<dim3(2 * NCHUNK), dim3(256), 0, stream>>>(E, g_w, b_w, ws);
    k3b_finish<<<dim3(1), dim3(256), 0, stream>>>(g_w, b_w, ws);
    k3c_write<<<dim3(2 * NCHUNK), dim3(256), 0, stream>>>(E, ws, out);
}